// Round 12
// baseline (29.473 us; speedup 1.0000x reference)
//
#include <hip/hip_runtime.h>

#define NUM_CLASSES 26
#define NBINS (NUM_CLASSES * NUM_CLASSES)   // 676 pair bins
#define SUBS 2                              // LDS sub-histograms (sub-major layout)
#define LDSN (SUBS * NBINS)                 // 1352 words = 5.4 KB
#define NCOUNT (3 * NUM_CLASSES)            // 78 logical counters
#define TPB 256

// ---------- shared inner loop ----------
// One ds_atomic per ELEMENT: pair bin idx = a*26 + b.
// F[c] = row sum, M[c] = col sum, I[c] = diagonal.
#define PROC_PAIR(aa, bb)                                                    \
    do {                                                                     \
        atomicAdd(&h[hb + ((aa).x * NUM_CLASSES + (bb).x)], 1u);             \
        atomicAdd(&h[hb + ((aa).y * NUM_CLASSES + (bb).y)], 1u);             \
        atomicAdd(&h[hb + ((aa).z * NUM_CLASSES + (bb).z)], 1u);             \
        atomicAdd(&h[hb + ((aa).w * NUM_CLASSES + (bb).w)], 1u);             \
    } while (0)

#define HIST_BODY                                                            \
    __shared__ unsigned int h[LDSN];                                         \
    for (int i = threadIdx.x; i < LDSN; i += TPB) h[i] = 0u;                 \
    __syncthreads();                                                         \
    const int tid      = blockIdx.x * TPB + threadIdx.x;                     \
    const int nthreads = gridDim.x * TPB;                                    \
    const int hb       = (threadIdx.x & (SUBS - 1)) * NBINS;                 \
    for (int base = tid; base < nfull; base += nthreads * 8) {               \
        int4 a[8], b[8];                                                     \
        _Pragma("unroll")                                                    \
        for (int k = 0; k < 8; ++k) a[k] = f4[base + k * nthreads];          \
        _Pragma("unroll")                                                    \
        for (int k = 0; k < 8; ++k) b[k] = m4[base + k * nthreads];          \
        _Pragma("unroll")                                                    \
        for (int k = 0; k < 8; ++k) {                                        \
            int4 aa = a[k], bb = b[k];                                       \
            PROC_PAIR(aa, bb);                                               \
        }                                                                    \
    }                                                                        \
    for (int i = nfull + tid; i < n4; i += nthreads) {                       \
        int4 aa = f4[i], bb = m4[i];                                         \
        PROC_PAIR(aa, bb);                                                   \
    }                                                                        \
    __syncthreads();

// ---------- main path: non-atomic per-block partials ----------
// amdgpu_waves_per_eu(2,2): cap occupancy at 2 waves/EU so the scheduler
// stops minimizing register pressure and keeps the 16-int4 batch clustered
// (R9/R10 profile: VGPR=32 -> batch demoted -> ~2 loads in flight -> 22 us).
__global__ __launch_bounds__(TPB)
__attribute__((amdgpu_waves_per_eu(2, 2)))
void sdl_hist_p(
    const int4* __restrict__ f4, const int4* __restrict__ m4,
    unsigned int* __restrict__ partials, float* __restrict__ out,
    int nblk, int n4, int nfull) {
    // init the output accumulator for the fin kernel (visible at kernel boundary)
    if (blockIdx.x == 0 && threadIdx.x == 0) out[0] = 1.0f;

    HIST_BODY

    const int t = threadIdx.x;
    const int b = blockIdx.x;
    if (t < NUM_CLASSES) {                         // wave 0: F[c] = row sum
        unsigned int v = 0;
        #pragma unroll
        for (int j = 0; j < NUM_CLASSES; ++j)
            v += h[t * NUM_CLASSES + j] + h[NBINS + t * NUM_CLASSES + j];
        partials[t * nblk + b] = v;
    } else if (t >= 64 && t < 64 + NUM_CLASSES) {  // wave 1: M[c] = col sum
        int c = t - 64;
        unsigned int v = 0;
        #pragma unroll
        for (int j = 0; j < NUM_CLASSES; ++j)
            v += h[j * NUM_CLASSES + c] + h[NBINS + j * NUM_CLASSES + c];
        partials[(NUM_CLASSES + c) * nblk + b] = v;
    } else if (t >= 128 && t < 128 + NUM_CLASSES) {  // wave 2: I[c] = diagonal
        int c = t - 128;
        partials[(2 * NUM_CLASSES + c) * nblk + b] =
            h[c * NUM_CLASSES + c] + h[NBINS + c * NUM_CLASSES + c];
    }
}

// Merged finalize: one block per CLASS (1..25), multi-CU spread (R10 proven).
__global__ __launch_bounds__(TPB) void sdl_fin(
    const unsigned int* __restrict__ partials, float* __restrict__ out, int nblk) {
    const int c = blockIdx.x + 1;                  // class 1..25
    const unsigned int* __restrict__ rF = partials + (size_t)c * nblk;
    const unsigned int* __restrict__ rM = partials + (size_t)(NUM_CLASSES + c) * nblk;
    const unsigned int* __restrict__ rI = partials + (size_t)(2 * NUM_CLASSES + c) * nblk;
    const int n4r = nblk >> 2;
    unsigned int sF = 0, sM = 0, sI = 0;

    if (n4r <= 2 * TPB) {                          // nblk <= 2048: all 6 loads in flight
        const int i0 = threadIdx.x, i1 = threadIdx.x + TPB;
        const bool h0 = i0 < n4r, h1 = i1 < n4r;
        uint4 f0, f1, m0, m1, q0, q1;
        if (h0) { f0 = ((const uint4*)rF)[i0]; m0 = ((const uint4*)rM)[i0]; q0 = ((const uint4*)rI)[i0]; }
        if (h1) { f1 = ((const uint4*)rF)[i1]; m1 = ((const uint4*)rM)[i1]; q1 = ((const uint4*)rI)[i1]; }
        if (h0) { sF += f0.x + f0.y + f0.z + f0.w; sM += m0.x + m0.y + m0.z + m0.w; sI += q0.x + q0.y + q0.z + q0.w; }
        if (h1) { sF += f1.x + f1.y + f1.z + f1.w; sM += m1.x + m1.y + m1.z + m1.w; sI += q1.x + q1.y + q1.z + q1.w; }
    } else {                                       // generic shape fallback
        for (int i = threadIdx.x; i < n4r; i += TPB) {
            uint4 f = ((const uint4*)rF)[i], m = ((const uint4*)rM)[i], q = ((const uint4*)rI)[i];
            sF += f.x + f.y + f.z + f.w;
            sM += m.x + m.y + m.z + m.w;
            sI += q.x + q.y + q.z + q.w;
        }
    }
    for (int w = (n4r << 2) + threadIdx.x; w < nblk; w += TPB) {  // row word tail
        sF += rF[w]; sM += rM[w]; sI += rI[w];
    }

    #pragma unroll
    for (int off = 32; off; off >>= 1) {
        sF += __shfl_down(sF, off, 64);
        sM += __shfl_down(sM, off, 64);
        sI += __shfl_down(sI, off, 64);
    }
    __shared__ unsigned int wF[4], wM[4], wI[4];
    const int wid = threadIdx.x >> 6;
    if ((threadIdx.x & 63) == 0) { wF[wid] = sF; wM[wid] = sM; wI[wid] = sI; }
    __syncthreads();
    if (threadIdx.x == 0) {
        const float eps = 1e-5f;
        float F = (float)(wF[0] + wF[1] + wF[2] + wF[3]);
        float M = (float)(wM[0] + wM[1] + wM[2] + wM[3]);
        float I = (float)(wI[0] + wI[1] + wI[2] + wI[3]);
        float term = (2.f * I + eps) / (F + M + eps);
        atomicAdd(out, -term * (1.f / (float)(NUM_CLASSES - 1)));
    }
}

// ---------- fallback path (tiny ws): proven R6 atomic scheme ----------
#define NREP 16
#define REPSTRIDE 80
#define GC_WORDS (NREP * REPSTRIDE)

__global__ void sdl_zero(unsigned int* __restrict__ c) {
    for (int i = threadIdx.x; i < GC_WORDS; i += TPB) c[i] = 0u;
}

__global__ __launch_bounds__(TPB, 2) void sdl_hist_a(
    const int4* __restrict__ f4, const int4* __restrict__ m4,
    unsigned int* __restrict__ gc, int n4, int nfull) {
    HIST_BODY

    unsigned int* rep = gc + (blockIdx.x & (NREP - 1)) * REPSTRIDE;
    const int t = threadIdx.x;
    if (t < NUM_CLASSES) {
        unsigned int v = 0;
        #pragma unroll
        for (int j = 0; j < NUM_CLASSES; ++j)
            v += h[t * NUM_CLASSES + j] + h[NBINS + t * NUM_CLASSES + j];
        if (v) atomicAdd(&rep[t], v);
    } else if (t >= 64 && t < 64 + NUM_CLASSES) {
        int c = t - 64;
        unsigned int v = 0;
        #pragma unroll
        for (int j = 0; j < NUM_CLASSES; ++j)
            v += h[j * NUM_CLASSES + c] + h[NBINS + j * NUM_CLASSES + c];
        if (v) atomicAdd(&rep[NUM_CLASSES + c], v);
    } else if (t >= 128 && t < 128 + NUM_CLASSES) {
        int c = t - 128;
        unsigned int v = h[c * NUM_CLASSES + c] + h[NBINS + c * NUM_CLASSES + c];
        if (v) atomicAdd(&rep[2 * NUM_CLASSES + c], v);
    }
}

__global__ void sdl_finalize_a(const unsigned int* __restrict__ gc,
                               float* __restrict__ out) {
    __shared__ float vals[NCOUNT];
    if (threadIdx.x < NCOUNT) {
        unsigned int v = 0;
        for (int r = 0; r < NREP; ++r) v += gc[r * REPSTRIDE + threadIdx.x];
        vals[threadIdx.x] = (float)v;
    }
    __syncthreads();
    if (threadIdx.x == 0) {
        const float eps = 1e-5f;
        float s = 0.f;
        for (int c = 1; c < NUM_CLASSES; ++c) {
            float F = vals[c];
            float M = vals[NUM_CLASSES + c];
            float I = vals[2 * NUM_CLASSES + c];
            s += (2.f * I + eps) / (F + M + eps);
        }
        out[0] = 1.f - s / (float)(NUM_CLASSES - 1);
    }
}

extern "C" void kernel_launch(void* const* d_in, const int* in_sizes, int n_in,
                              void* d_out, int out_size, void* d_ws, size_t ws_size,
                              hipStream_t stream) {
    const int* f = (const int*)d_in[0];
    const int* m = (const int*)d_in[1];
    float* out = (float*)d_out;

    int n  = in_sizes[0];         // 14,155,776 (divisible by 4)
    int n4 = n / 4;               // 3,538,944 int4-pairs

    int blocks = n4 / (TPB * 8);  // 1728: each thread exactly one 8-pair batch
    if (blocks < 1) blocks = 1;
    if (blocks > 4096) blocks = 4096;

    size_t need = (size_t)NCOUNT * blocks * sizeof(unsigned int);
    if (ws_size >= need) {
        // main path: 2 dispatches, no zeroing, no integer atomics in flush
        unsigned int* partials = (unsigned int*)d_ws;
        int nthreads = blocks * TPB;
        int nfull = (n4 / (nthreads * 8)) * (nthreads * 8);
        sdl_hist_p<<<blocks, TPB, 0, stream>>>((const int4*)f, (const int4*)m,
                                               partials, out, blocks, n4, nfull);
        sdl_fin<<<NUM_CLASSES - 1, TPB, 0, stream>>>(partials, out, blocks);
    } else {
        // fallback: proven R6 atomic scheme (needs only 5 KB)
        unsigned int* gc = (unsigned int*)d_ws;
        int nthreads = blocks * TPB;
        int nfull = (n4 / (nthreads * 8)) * (nthreads * 8);
        sdl_zero<<<1, TPB, 0, stream>>>(gc);
        sdl_hist_a<<<blocks, TPB, 0, stream>>>((const int4*)f, (const int4*)m,
                                               gc, n4, nfull);
        sdl_finalize_a<<<1, 128, 0, stream>>>(gc, out);
    }
}

// Round 13
// 25.697 us; speedup vs baseline: 1.1469x; 1.1469x over previous
//
#include <hip/hip_runtime.h>

#define NUM_CLASSES 26
#define NBINS (NUM_CLASSES * NUM_CLASSES)   // 676 pair bins
#define SUBS 2                              // LDS sub-histograms (sub-major layout)
#define LDSN (SUBS * NBINS)                 // 1352 words = 5.4 KB
#define NCOUNT (3 * NUM_CLASSES)            // 78 logical counters
#define TPB 256

// ---------- shared inner loop ----------
// One ds_atomic per ELEMENT: pair bin idx = a*26 + b.
// F[c] = row sum, M[c] = col sum, I[c] = diagonal.
#define PROC_PAIR(aa, bb)                                                    \
    do {                                                                     \
        atomicAdd(&h[hb + ((aa).x * NUM_CLASSES + (bb).x)], 1u);             \
        atomicAdd(&h[hb + ((aa).y * NUM_CLASSES + (bb).y)], 1u);             \
        atomicAdd(&h[hb + ((aa).z * NUM_CLASSES + (bb).z)], 1u);             \
        atomicAdd(&h[hb + ((aa).w * NUM_CLASSES + (bb).w)], 1u);             \
    } while (0)

#define HIST_BODY                                                            \
    __shared__ unsigned int h[LDSN];                                         \
    for (int i = threadIdx.x; i < LDSN; i += TPB) h[i] = 0u;                 \
    __syncthreads();                                                         \
    const int tid      = blockIdx.x * TPB + threadIdx.x;                     \
    const int nthreads = gridDim.x * TPB;                                    \
    const int hb       = (threadIdx.x & (SUBS - 1)) * NBINS;                 \
    for (int base = tid; base < nfull; base += nthreads * 8) {               \
        int4 a[8], b[8];                                                     \
        _Pragma("unroll")                                                    \
        for (int k = 0; k < 8; ++k) a[k] = f4[base + k * nthreads];          \
        _Pragma("unroll")                                                    \
        for (int k = 0; k < 8; ++k) b[k] = m4[base + k * nthreads];          \
        _Pragma("unroll")                                                    \
        for (int k = 0; k < 8; ++k) {                                        \
            int4 aa = a[k], bb = b[k];                                       \
            PROC_PAIR(aa, bb);                                               \
        }                                                                    \
    }                                                                        \
    for (int i = nfull + tid; i < n4; i += nthreads) {                       \
        int4 aa = f4[i], bb = m4[i];                                         \
        PROC_PAIR(aa, bb);                                                   \
    }                                                                        \
    __syncthreads();

// ---------- main path: non-atomic per-block partials (R11 config: proven 25.9 us) ----------
// NOTE: no waves_per_eu attribute. R12 showed VGPR=88/occ=17% is SLOWER than
// VGPR=32/occ=53% — TLP across ~17 waves/CU already sustains 5.05 TB/s (80% of
// the 6.29 TB/s copy ceiling); trading occupancy for per-wave ILP regresses.
__global__ __launch_bounds__(TPB, 2) void sdl_hist_p(
    const int4* __restrict__ f4, const int4* __restrict__ m4,
    unsigned int* __restrict__ partials, float* __restrict__ out,
    int nblk, int n4, int nfull) {
    // init the output accumulator for the fin kernel (visible at kernel boundary)
    if (blockIdx.x == 0 && threadIdx.x == 0) out[0] = 1.0f;

    HIST_BODY

    const int t = threadIdx.x;
    const int b = blockIdx.x;
    if (t < NUM_CLASSES) {                         // wave 0: F[c] = row sum
        unsigned int v = 0;
        #pragma unroll
        for (int j = 0; j < NUM_CLASSES; ++j)
            v += h[t * NUM_CLASSES + j] + h[NBINS + t * NUM_CLASSES + j];
        partials[t * nblk + b] = v;
    } else if (t >= 64 && t < 64 + NUM_CLASSES) {  // wave 1: M[c] = col sum
        int c = t - 64;
        unsigned int v = 0;
        #pragma unroll
        for (int j = 0; j < NUM_CLASSES; ++j)
            v += h[j * NUM_CLASSES + c] + h[NBINS + j * NUM_CLASSES + c];
        partials[(NUM_CLASSES + c) * nblk + b] = v;
    } else if (t >= 128 && t < 128 + NUM_CLASSES) {  // wave 2: I[c] = diagonal
        int c = t - 128;
        partials[(2 * NUM_CLASSES + c) * nblk + b] =
            h[c * NUM_CLASSES + c] + h[NBINS + c * NUM_CLASSES + c];
    }
}

// Merged finalize: one block per CLASS (1..25), multi-CU spread (R10 proven).
__global__ __launch_bounds__(TPB) void sdl_fin(
    const unsigned int* __restrict__ partials, float* __restrict__ out, int nblk) {
    const int c = blockIdx.x + 1;                  // class 1..25
    const unsigned int* __restrict__ rF = partials + (size_t)c * nblk;
    const unsigned int* __restrict__ rM = partials + (size_t)(NUM_CLASSES + c) * nblk;
    const unsigned int* __restrict__ rI = partials + (size_t)(2 * NUM_CLASSES + c) * nblk;
    const int n4r = nblk >> 2;
    unsigned int sF = 0, sM = 0, sI = 0;

    if (n4r <= 2 * TPB) {                          // nblk <= 2048: all 6 loads in flight
        const int i0 = threadIdx.x, i1 = threadIdx.x + TPB;
        const bool h0 = i0 < n4r, h1 = i1 < n4r;
        uint4 f0, f1, m0, m1, q0, q1;
        if (h0) { f0 = ((const uint4*)rF)[i0]; m0 = ((const uint4*)rM)[i0]; q0 = ((const uint4*)rI)[i0]; }
        if (h1) { f1 = ((const uint4*)rF)[i1]; m1 = ((const uint4*)rM)[i1]; q1 = ((const uint4*)rI)[i1]; }
        if (h0) { sF += f0.x + f0.y + f0.z + f0.w; sM += m0.x + m0.y + m0.z + m0.w; sI += q0.x + q0.y + q0.z + q0.w; }
        if (h1) { sF += f1.x + f1.y + f1.z + f1.w; sM += m1.x + m1.y + m1.z + m1.w; sI += q1.x + q1.y + q1.z + q1.w; }
    } else {                                       // generic shape fallback
        for (int i = threadIdx.x; i < n4r; i += TPB) {
            uint4 f = ((const uint4*)rF)[i], m = ((const uint4*)rM)[i], q = ((const uint4*)rI)[i];
            sF += f.x + f.y + f.z + f.w;
            sM += m.x + m.y + m.z + m.w;
            sI += q.x + q.y + q.z + q.w;
        }
    }
    for (int w = (n4r << 2) + threadIdx.x; w < nblk; w += TPB) {  // row word tail
        sF += rF[w]; sM += rM[w]; sI += rI[w];
    }

    #pragma unroll
    for (int off = 32; off; off >>= 1) {
        sF += __shfl_down(sF, off, 64);
        sM += __shfl_down(sM, off, 64);
        sI += __shfl_down(sI, off, 64);
    }
    __shared__ unsigned int wF[4], wM[4], wI[4];
    const int wid = threadIdx.x >> 6;
    if ((threadIdx.x & 63) == 0) { wF[wid] = sF; wM[wid] = sM; wI[wid] = sI; }
    __syncthreads();
    if (threadIdx.x == 0) {
        const float eps = 1e-5f;
        float F = (float)(wF[0] + wF[1] + wF[2] + wF[3]);
        float M = (float)(wM[0] + wM[1] + wM[2] + wM[3]);
        float I = (float)(wI[0] + wI[1] + wI[2] + wI[3]);
        float term = (2.f * I + eps) / (F + M + eps);
        atomicAdd(out, -term * (1.f / (float)(NUM_CLASSES - 1)));
    }
}

// ---------- fallback path (tiny ws): proven R6 atomic scheme ----------
#define NREP 16
#define REPSTRIDE 80
#define GC_WORDS (NREP * REPSTRIDE)

__global__ void sdl_zero(unsigned int* __restrict__ c) {
    for (int i = threadIdx.x; i < GC_WORDS; i += TPB) c[i] = 0u;
}

__global__ __launch_bounds__(TPB, 2) void sdl_hist_a(
    const int4* __restrict__ f4, const int4* __restrict__ m4,
    unsigned int* __restrict__ gc, int n4, int nfull) {
    HIST_BODY

    unsigned int* rep = gc + (blockIdx.x & (NREP - 1)) * REPSTRIDE;
    const int t = threadIdx.x;
    if (t < NUM_CLASSES) {
        unsigned int v = 0;
        #pragma unroll
        for (int j = 0; j < NUM_CLASSES; ++j)
            v += h[t * NUM_CLASSES + j] + h[NBINS + t * NUM_CLASSES + j];
        if (v) atomicAdd(&rep[t], v);
    } else if (t >= 64 && t < 64 + NUM_CLASSES) {
        int c = t - 64;
        unsigned int v = 0;
        #pragma unroll
        for (int j = 0; j < NUM_CLASSES; ++j)
            v += h[j * NUM_CLASSES + c] + h[NBINS + j * NUM_CLASSES + c];
        if (v) atomicAdd(&rep[NUM_CLASSES + c], v);
    } else if (t >= 128 && t < 128 + NUM_CLASSES) {
        int c = t - 128;
        unsigned int v = h[c * NUM_CLASSES + c] + h[NBINS + c * NUM_CLASSES + c];
        if (v) atomicAdd(&rep[2 * NUM_CLASSES + c], v);
    }
}

__global__ void sdl_finalize_a(const unsigned int* __restrict__ gc,
                               float* __restrict__ out) {
    __shared__ float vals[NCOUNT];
    if (threadIdx.x < NCOUNT) {
        unsigned int v = 0;
        for (int r = 0; r < NREP; ++r) v += gc[r * REPSTRIDE + threadIdx.x];
        vals[threadIdx.x] = (float)v;
    }
    __syncthreads();
    if (threadIdx.x == 0) {
        const float eps = 1e-5f;
        float s = 0.f;
        for (int c = 1; c < NUM_CLASSES; ++c) {
            float F = vals[c];
            float M = vals[NUM_CLASSES + c];
            float I = vals[2 * NUM_CLASSES + c];
            s += (2.f * I + eps) / (F + M + eps);
        }
        out[0] = 1.f - s / (float)(NUM_CLASSES - 1);
    }
}

extern "C" void kernel_launch(void* const* d_in, const int* in_sizes, int n_in,
                              void* d_out, int out_size, void* d_ws, size_t ws_size,
                              hipStream_t stream) {
    const int* f = (const int*)d_in[0];
    const int* m = (const int*)d_in[1];
    float* out = (float*)d_out;

    int n  = in_sizes[0];         // 14,155,776 (divisible by 4)
    int n4 = n / 4;               // 3,538,944 int4-pairs

    int blocks = n4 / (TPB * 8);  // 1728: each thread exactly one 8-pair batch
    if (blocks < 1) blocks = 1;
    if (blocks > 4096) blocks = 4096;

    size_t need = (size_t)NCOUNT * blocks * sizeof(unsigned int);
    if (ws_size >= need) {
        // main path: 2 dispatches, no zeroing, no integer atomics in flush
        unsigned int* partials = (unsigned int*)d_ws;
        int nthreads = blocks * TPB;
        int nfull = (n4 / (nthreads * 8)) * (nthreads * 8);
        sdl_hist_p<<<blocks, TPB, 0, stream>>>((const int4*)f, (const int4*)m,
                                               partials, out, blocks, n4, nfull);
        sdl_fin<<<NUM_CLASSES - 1, TPB, 0, stream>>>(partials, out, blocks);
    } else {
        // fallback: proven R6 atomic scheme (needs only 5 KB)
        unsigned int* gc = (unsigned int*)d_ws;
        int nthreads = blocks * TPB;
        int nfull = (n4 / (nthreads * 8)) * (nthreads * 8);
        sdl_zero<<<1, TPB, 0, stream>>>(gc);
        sdl_hist_a<<<blocks, TPB, 0, stream>>>((const int4*)f, (const int4*)m,
                                               gc, n4, nfull);
        sdl_finalize_a<<<1, 128, 0, stream>>>(gc, out);
    }
}